// Round 4
// baseline (253.504 us; speedup 1.0000x reference)
//
#include <hip/hip_runtime.h>

// VQ straight-through: B=32, V=4096, D=64, K=512. N = 131072 rows.
// Outputs (flat, concatenated): z_q_st [N,D] f32, z_q [N,D] f32, indices [N] (as f32).
//
// Correctness contract (established R2/R3, passing): replicate numpy fp32 bitwise —
//  - sums of squares: numpy pairwise_sum scalar 8-accumulator order, products
//    rounded separately (no FMA contraction into the sum)
//  - z@e.T dots: sequential single-accumulator FMA chain over d=0..63 (BLAS)
//  - d2 = fl(fl(A - 2*dot) + C); argmin k-ascending, strict < (first min)
//
// R9: R8 proved __launch_bounds__(256,3) is only a register CAP — the
// scheduler still TARGETS high occupancy, so it remats z (VGPR stayed 40,
// dur 170-178us). This round sets the occupancy GOAL itself:
//  (a) __attribute__((amdgpu_waves_per_eu(2,4))): max 4 waves/EU -> pressure
//      target 128 VGPRs -> z[64]+acc+misc (~88) fits WITHIN target, remat
//      heuristic has no trigger. Measured occupancy was already ~49% (~4
//      waves/EU), so the cap costs nothing.
//  (b) one-time launder of z through four 16-operand empty asms after the
//      A-computation: k-loop z uses are data-dependent on opaque asm outputs,
//      so remat of the global loads is ILLEGAL by construction (unlike R5's
//      per-iteration pins, this forces nothing inside the loop).
// Numerics op-for-op identical to R8 (launder is identity; attr is metadata).

#define VQ_N (32 * 4096)
#define VQ_D 64
#define VQ_K 512

// Rounding barrier: forbids FMA contraction / reassociation through x.
__device__ __forceinline__ float freeze(float x) {
  asm volatile("" : "+v"(x));
  return x;
}

// ---- kernel 1: C_k = np.sum(emb*emb, -1) in numpy fp32 order ----
__global__ __launch_bounds__(256) void vq_norms_kernel(
    const float* __restrict__ emb, float* __restrict__ nrm) {
  int k = blockIdx.x * blockDim.x + threadIdx.x;
  if (k < VQ_K) {
    const float* e = emb + k * VQ_D;
    float r0 = freeze(e[0] * e[0]), r1 = freeze(e[1] * e[1]);
    float r2 = freeze(e[2] * e[2]), r3 = freeze(e[3] * e[3]);
    float r4 = freeze(e[4] * e[4]), r5 = freeze(e[5] * e[5]);
    float r6 = freeze(e[6] * e[6]), r7 = freeze(e[7] * e[7]);
#pragma unroll
    for (int i = 8; i < VQ_D; i += 8) {
      r0 += freeze(e[i + 0] * e[i + 0]); r1 += freeze(e[i + 1] * e[i + 1]);
      r2 += freeze(e[i + 2] * e[i + 2]); r3 += freeze(e[i + 3] * e[i + 3]);
      r4 += freeze(e[i + 4] * e[i + 4]); r5 += freeze(e[i + 5] * e[i + 5]);
      r6 += freeze(e[i + 6] * e[i + 6]); r7 += freeze(e[i + 7] * e[i + 7]);
    }
    nrm[k] = ((r0 + r1) + (r2 + r3)) + ((r4 + r5) + (r6 + r7));
  }
}

// ---- kernel 2: main — 64 rows/block, K split across the 4 waves ----
__global__ __launch_bounds__(256)
__attribute__((amdgpu_waves_per_eu(2, 4))) void vq_main_kernel(
    const float* __restrict__ z_e, const float* __restrict__ emb,
    const float* __restrict__ nrm, float* __restrict__ out_st,
    float* __restrict__ out_q, float* __restrict__ out_idx) {
  __shared__ float s_val[256];  // per (chunk, row) partial best value
  __shared__ int s_idx[256];    // per (chunk, row) partial best index
  __shared__ int s_best[64];    // final best index per row

  const int tid = threadIdx.x;
  const int lane = tid & 63;                                   // row in block
  const int chunk = __builtin_amdgcn_readfirstlane(tid >> 6);  // wave-uniform
  const int row = blockIdx.x * 64 + lane;

  // Row into registers.
  float z[VQ_D];
  const float4* z4 = (const float4*)(z_e + (size_t)row * VQ_D);
#pragma unroll
  for (int j = 0; j < 16; ++j) {
    float4 v = z4[j];
    z[4 * j + 0] = v.x; z[4 * j + 1] = v.y;
    z[4 * j + 2] = v.z; z[4 * j + 3] = v.w;
  }

  // A = np.sum(z*z) in numpy 8-accumulator order; products rounded separately.
  float r0 = freeze(z[0] * z[0]), r1 = freeze(z[1] * z[1]);
  float r2 = freeze(z[2] * z[2]), r3 = freeze(z[3] * z[3]);
  float r4 = freeze(z[4] * z[4]), r5 = freeze(z[5] * z[5]);
  float r6 = freeze(z[6] * z[6]), r7 = freeze(z[7] * z[7]);
#pragma unroll
  for (int i = 8; i < VQ_D; i += 8) {
    r0 += freeze(z[i + 0] * z[i + 0]); r1 += freeze(z[i + 1] * z[i + 1]);
    r2 += freeze(z[i + 2] * z[i + 2]); r3 += freeze(z[i + 3] * z[i + 3]);
    r4 += freeze(z[i + 4] * z[i + 4]); r5 += freeze(z[i + 5] * z[i + 5]);
    r6 += freeze(z[i + 6] * z[i + 6]); r7 += freeze(z[i + 7] * z[i + 7]);
  }
  const float A = ((r0 + r1) + (r2 + r3)) + ((r4 + r5) + (r6 + r7));

  // One-time launder: k-loop z uses depend on opaque asm outputs -> global
  // loads cannot be rematerialized inside the loop. Identity, 0 instructions.
#define VQ_PIN16(B)                                                        \
  asm volatile(""                                                          \
               : "+v"(z[B + 0]), "+v"(z[B + 1]), "+v"(z[B + 2]),           \
                 "+v"(z[B + 3]), "+v"(z[B + 4]), "+v"(z[B + 5]),           \
                 "+v"(z[B + 6]), "+v"(z[B + 7]), "+v"(z[B + 8]),           \
                 "+v"(z[B + 9]), "+v"(z[B + 10]), "+v"(z[B + 11]),         \
                 "+v"(z[B + 12]), "+v"(z[B + 13]), "+v"(z[B + 14]),        \
                 "+v"(z[B + 15]))
  VQ_PIN16(0);
  VQ_PIN16(16);
  VQ_PIN16(32);
  VQ_PIN16(48);
#undef VQ_PIN16

  // Scan this wave's 128 codes, 4 at a time (4 independent FMA chains).
  // e-row addresses are wave-uniform (kk from readfirstlane'd chunk), so the
  // compiler selects scalar s_load for the e-stream (SGPR_Count=112).
  const int k0 = chunk * (VQ_K / 4);
  float bestv = 3.4e38f;
  int best = k0;
  for (int kk = k0; kk < k0 + VQ_K / 4; kk += 4) {
    const float* e0 = emb + (size_t)(kk + 0) * VQ_D;
    const float* e1 = emb + (size_t)(kk + 1) * VQ_D;
    const float* e2 = emb + (size_t)(kk + 2) * VQ_D;
    const float* e3 = emb + (size_t)(kk + 3) * VQ_D;
    float a0 = 0.f, a1 = 0.f, a2 = 0.f, a3 = 0.f;
#pragma unroll
    for (int d = 0; d < VQ_D; ++d) {
      a0 = fmaf(z[d], e0[d], a0);  // sequential FMA, d ascending (BLAS order)
      a1 = fmaf(z[d], e1[d], a1);
      a2 = fmaf(z[d], e2[d], a2);
      a3 = fmaf(z[d], e3[d], a3);
    }
    // d2 = fl(fl(A - 2*dot) + C); 2*dot exact => fmaf(-2,a,A) == fl(A-2a).
    float t0 = fmaf(-2.0f, a0, A) + nrm[kk + 0];
    float t1 = fmaf(-2.0f, a1, A) + nrm[kk + 1];
    float t2 = fmaf(-2.0f, a2, A) + nrm[kk + 2];
    float t3 = fmaf(-2.0f, a3, A) + nrm[kk + 3];
    if (t0 < bestv) { bestv = t0; best = kk + 0; }
    if (t1 < bestv) { bestv = t1; best = kk + 1; }
    if (t2 < bestv) { bestv = t2; best = kk + 2; }
    if (t3 < bestv) { bestv = t3; best = kk + 3; }
  }

  s_val[chunk * 64 + lane] = bestv;
  s_idx[chunk * 64 + lane] = best;
  __syncthreads();

  // Cross-chunk argmin per row: ascending chunk order + strict < keeps the
  // lowest-index minimum (chunk c's indices all < chunk c+1's) == np.argmin.
  if (tid < 64) {
    float v = s_val[tid];
    int b = s_idx[tid];
#pragma unroll
    for (int c = 1; c < 4; ++c) {
      float vc = s_val[c * 64 + tid];
      if (vc < v) { v = vc; b = s_idx[c * 64 + tid]; }
    }
    s_best[tid] = b;
    out_idx[row] = (float)b;
  }
  __syncthreads();

  // Coalesced output writes: 64 rows x 16 float4 per array.
  const float4* e4 = (const float4*)emb;
  const size_t base4 = (size_t)blockIdx.x * 64 * 16;
  float4* o0 = (float4*)out_st;
  float4* o1 = (float4*)out_q;
#pragma unroll
  for (int t = 0; t < 4; ++t) {
    int i = t * 256 + tid;
    int r = i >> 4, j = i & 15;
    float4 v = e4[s_best[r] * 16 + j];
    o0[base4 + i] = v;
    o1[base4 + i] = v;
  }
}

extern "C" void kernel_launch(void* const* d_in, const int* in_sizes, int n_in,
                              void* d_out, int out_size, void* d_ws,
                              size_t ws_size, hipStream_t stream) {
  const float* z_e = (const float*)d_in[0];  // [N, D] fp32
  const float* emb = (const float*)d_in[1];  // [K, D] fp32
  float* nrm = (float*)d_ws;                 // [K] fp32 scratch

  float* out_st = (float*)d_out;                 // [N, D]
  float* out_q = out_st + (size_t)VQ_N * VQ_D;   // [N, D]
  float* out_idx = out_q + (size_t)VQ_N * VQ_D;  // [N] as float

  vq_norms_kernel<<<(VQ_K + 255) / 256, 256, 0, stream>>>(emb, nrm);
  vq_main_kernel<<<VQ_N / 64, 256, 0, stream>>>(z_e, emb, nrm, out_st, out_q,
                                                out_idx);
}

// Round 5
// 237.382 us; speedup vs baseline: 1.0679x; 1.0679x over previous
//
#include <hip/hip_runtime.h>

// VQ straight-through: B=32, V=4096, D=64, K=512. N = 131072 rows.
// Outputs (flat, concatenated): z_q_st [N,D] f32, z_q [N,D] f32, indices [N] (as f32).
//
// Correctness contract (established R2/R3, passing): replicate numpy fp32 bitwise —
//  - sums of squares: numpy pairwise_sum scalar 8-accumulator order, products
//    rounded separately (no FMA contraction into the sum)
//  - z@e.T dots: sequential single-accumulator FMA chain over d=0..63 (BLAS)
//  - d2 = fl(fl(A - 2*dot) + C); argmin k-ascending, strict < (first min)
//
// R10: R5..R9 proved the "keep z[64] in VGPRs" fight is unwinnable from
// source: every launch-bound/pin/launder variant lands at 170-183us with the
// allocator reloading z (VGPR 40-52). Structural fix: z lives in LDS.
//  - Stage the block's 64x64 z-tile once into __shared__ float4 z_lds[16][64]
//    (16 KB, coalesced float4 global reads).
//  - k-loop re-reads the row chunk-by-chunk: ds_read_b128 at lane-stride 16B
//    (dense 1KB/wave = the 8-cyc LDS minimum, conflict-free). Per-thread
//    registers: ~8 acc + 1 float4 + misc ≈ 40 VGPR -> fits the compiler's
//    default occupancy target; nothing left to rematerialize.
//  - Code-groups widened 4->8 chains: halves lgkm-wait convoys per FMA and
//    doubles z-read reuse (16 b128 serve 512 FMAs).
//  - e-stream unchanged plain-C idiom (compiler lowers to s_load; SGPR=112).
// Numerics bit-identical: LDS round-trip preserves bits; A's freeze'd
// 8-accumulator order fed chunk-pairwise (same d=8i+j mapping); dots remain
// single-acc sequential d=0..63 ascending; argmin same comparisons, same order.

#define VQ_N (32 * 4096)
#define VQ_D 64
#define VQ_K 512

// Rounding barrier: forbids FMA contraction / reassociation through x.
__device__ __forceinline__ float freeze(float x) {
  asm volatile("" : "+v"(x));
  return x;
}

// ---- kernel 1: C_k = np.sum(emb*emb, -1) in numpy fp32 order ----
__global__ __launch_bounds__(256) void vq_norms_kernel(
    const float* __restrict__ emb, float* __restrict__ nrm) {
  int k = blockIdx.x * blockDim.x + threadIdx.x;
  if (k < VQ_K) {
    const float* e = emb + k * VQ_D;
    float r0 = freeze(e[0] * e[0]), r1 = freeze(e[1] * e[1]);
    float r2 = freeze(e[2] * e[2]), r3 = freeze(e[3] * e[3]);
    float r4 = freeze(e[4] * e[4]), r5 = freeze(e[5] * e[5]);
    float r6 = freeze(e[6] * e[6]), r7 = freeze(e[7] * e[7]);
#pragma unroll
    for (int i = 8; i < VQ_D; i += 8) {
      r0 += freeze(e[i + 0] * e[i + 0]); r1 += freeze(e[i + 1] * e[i + 1]);
      r2 += freeze(e[i + 2] * e[i + 2]); r3 += freeze(e[i + 3] * e[i + 3]);
      r4 += freeze(e[i + 4] * e[i + 4]); r5 += freeze(e[i + 5] * e[i + 5]);
      r6 += freeze(e[i + 6] * e[i + 6]); r7 += freeze(e[i + 7] * e[i + 7]);
    }
    nrm[k] = ((r0 + r1) + (r2 + r3)) + ((r4 + r5) + (r6 + r7));
  }
}

// ---- kernel 2: main — 64 rows/block, K split across the 4 waves ----
__global__ __launch_bounds__(256) void vq_main_kernel(
    const float* __restrict__ z_e, const float* __restrict__ emb,
    const float* __restrict__ nrm, float* __restrict__ out_st,
    float* __restrict__ out_q, float* __restrict__ out_idx) {
  __shared__ float4 z_lds[16][64];  // [d-chunk][row] : 16 KB z tile
  __shared__ float s_val[256];      // per (chunk, row) partial best value
  __shared__ int s_idx[256];        // per (chunk, row) partial best index
  __shared__ int s_best[64];        // final best index per row

  const int tid = threadIdx.x;
  const int lane = tid & 63;                                   // row in block
  const int chunk = __builtin_amdgcn_readfirstlane(tid >> 6);  // wave-uniform
  const int row0 = blockIdx.x * 64;
  const int row = row0 + lane;

  // Stage z tile: 1024 float4s, coalesced (thread i -> row i>>4, chunk i&15).
  const float4* zg = (const float4*)(z_e + (size_t)row0 * VQ_D);
#pragma unroll
  for (int t = 0; t < 4; ++t) {
    int i = t * 256 + tid;
    z_lds[i & 15][i >> 4] = zg[i];
  }
  __syncthreads();

  // A = np.sum(z*z) in numpy 8-accumulator order (acc j gets d ≡ j mod 8);
  // chunk pair (2c, 2c+1) supplies d = 8c..8c+7. Products rounded separately.
  float r0, r1, r2, r3, r4, r5, r6, r7;
  {
    float4 p0 = z_lds[0][lane], p1 = z_lds[1][lane];
    r0 = freeze(p0.x * p0.x); r1 = freeze(p0.y * p0.y);
    r2 = freeze(p0.z * p0.z); r3 = freeze(p0.w * p0.w);
    r4 = freeze(p1.x * p1.x); r5 = freeze(p1.y * p1.y);
    r6 = freeze(p1.z * p1.z); r7 = freeze(p1.w * p1.w);
#pragma unroll
    for (int c = 2; c < 16; c += 2) {
      float4 q0 = z_lds[c][lane], q1 = z_lds[c + 1][lane];
      r0 += freeze(q0.x * q0.x); r1 += freeze(q0.y * q0.y);
      r2 += freeze(q0.z * q0.z); r3 += freeze(q0.w * q0.w);
      r4 += freeze(q1.x * q1.x); r5 += freeze(q1.y * q1.y);
      r6 += freeze(q1.z * q1.z); r7 += freeze(q1.w * q1.w);
    }
  }
  const float A = ((r0 + r1) + (r2 + r3)) + ((r4 + r5) + (r6 + r7));

  // Scan this wave's 128 codes, 8 at a time (8 independent FMA chains).
  // z chunks re-read from LDS per group (dense b128, conflict-free); e-rows
  // are wave-uniform -> scalar s_load stream (SGPR evidence from R5).
  const int k0 = chunk * (VQ_K / 4);
  float bestv = 3.4e38f;
  int best = k0;
  for (int kk = k0; kk < k0 + VQ_K / 4; kk += 8) {
    const float* e0 = emb + (size_t)(kk + 0) * VQ_D;
    const float* e1 = emb + (size_t)(kk + 1) * VQ_D;
    const float* e2 = emb + (size_t)(kk + 2) * VQ_D;
    const float* e3 = emb + (size_t)(kk + 3) * VQ_D;
    const float* e4 = emb + (size_t)(kk + 4) * VQ_D;
    const float* e5 = emb + (size_t)(kk + 5) * VQ_D;
    const float* e6 = emb + (size_t)(kk + 6) * VQ_D;
    const float* e7 = emb + (size_t)(kk + 7) * VQ_D;
    float a0 = 0.f, a1 = 0.f, a2 = 0.f, a3 = 0.f;
    float a4 = 0.f, a5 = 0.f, a6 = 0.f, a7 = 0.f;
#pragma unroll
    for (int c = 0; c < 16; ++c) {  // d = 4c..4c+3, ascending per accumulator
      float4 zc = z_lds[c][lane];
      a0 = fmaf(zc.x, e0[4 * c + 0], a0); a0 = fmaf(zc.y, e0[4 * c + 1], a0);
      a0 = fmaf(zc.z, e0[4 * c + 2], a0); a0 = fmaf(zc.w, e0[4 * c + 3], a0);
      a1 = fmaf(zc.x, e1[4 * c + 0], a1); a1 = fmaf(zc.y, e1[4 * c + 1], a1);
      a1 = fmaf(zc.z, e1[4 * c + 2], a1); a1 = fmaf(zc.w, e1[4 * c + 3], a1);
      a2 = fmaf(zc.x, e2[4 * c + 0], a2); a2 = fmaf(zc.y, e2[4 * c + 1], a2);
      a2 = fmaf(zc.z, e2[4 * c + 2], a2); a2 = fmaf(zc.w, e2[4 * c + 3], a2);
      a3 = fmaf(zc.x, e3[4 * c + 0], a3); a3 = fmaf(zc.y, e3[4 * c + 1], a3);
      a3 = fmaf(zc.z, e3[4 * c + 2], a3); a3 = fmaf(zc.w, e3[4 * c + 3], a3);
      a4 = fmaf(zc.x, e4[4 * c + 0], a4); a4 = fmaf(zc.y, e4[4 * c + 1], a4);
      a4 = fmaf(zc.z, e4[4 * c + 2], a4); a4 = fmaf(zc.w, e4[4 * c + 3], a4);
      a5 = fmaf(zc.x, e5[4 * c + 0], a5); a5 = fmaf(zc.y, e5[4 * c + 1], a5);
      a5 = fmaf(zc.z, e5[4 * c + 2], a5); a5 = fmaf(zc.w, e5[4 * c + 3], a5);
      a6 = fmaf(zc.x, e6[4 * c + 0], a6); a6 = fmaf(zc.y, e6[4 * c + 1], a6);
      a6 = fmaf(zc.z, e6[4 * c + 2], a6); a6 = fmaf(zc.w, e6[4 * c + 3], a6);
      a7 = fmaf(zc.x, e7[4 * c + 0], a7); a7 = fmaf(zc.y, e7[4 * c + 1], a7);
      a7 = fmaf(zc.z, e7[4 * c + 2], a7); a7 = fmaf(zc.w, e7[4 * c + 3], a7);
    }
    // d2 = fl(fl(A - 2*dot) + C); 2*dot exact => fmaf(-2,a,A) == fl(A-2a).
    float t0 = fmaf(-2.0f, a0, A) + nrm[kk + 0];
    float t1 = fmaf(-2.0f, a1, A) + nrm[kk + 1];
    float t2 = fmaf(-2.0f, a2, A) + nrm[kk + 2];
    float t3 = fmaf(-2.0f, a3, A) + nrm[kk + 3];
    float t4 = fmaf(-2.0f, a4, A) + nrm[kk + 4];
    float t5 = fmaf(-2.0f, a5, A) + nrm[kk + 5];
    float t6 = fmaf(-2.0f, a6, A) + nrm[kk + 6];
    float t7 = fmaf(-2.0f, a7, A) + nrm[kk + 7];
    if (t0 < bestv) { bestv = t0; best = kk + 0; }
    if (t1 < bestv) { bestv = t1; best = kk + 1; }
    if (t2 < bestv) { bestv = t2; best = kk + 2; }
    if (t3 < bestv) { bestv = t3; best = kk + 3; }
    if (t4 < bestv) { bestv = t4; best = kk + 4; }
    if (t5 < bestv) { bestv = t5; best = kk + 5; }
    if (t6 < bestv) { bestv = t6; best = kk + 6; }
    if (t7 < bestv) { bestv = t7; best = kk + 7; }
  }

  s_val[chunk * 64 + lane] = bestv;
  s_idx[chunk * 64 + lane] = best;
  __syncthreads();

  // Cross-chunk argmin per row: ascending chunk order + strict < keeps the
  // lowest-index minimum (chunk c's indices all < chunk c+1's) == np.argmin.
  if (tid < 64) {
    float v = s_val[tid];
    int b = s_idx[tid];
#pragma unroll
    for (int c = 1; c < 4; ++c) {
      float vc = s_val[c * 64 + tid];
      if (vc < v) { v = vc; b = s_idx[c * 64 + tid]; }
    }
    s_best[tid] = b;
    out_idx[row] = (float)b;
  }
  __syncthreads();

  // Coalesced output writes: 64 rows x 16 float4 per array.
  const float4* eg4 = (const float4*)emb;
  const size_t base4 = (size_t)blockIdx.x * 64 * 16;
  float4* o0 = (float4*)out_st;
  float4* o1 = (float4*)out_q;
#pragma unroll
  for (int t = 0; t < 4; ++t) {
    int i = t * 256 + tid;
    int r = i >> 4, j = i & 15;
    float4 v = eg4[s_best[r] * 16 + j];
    o0[base4 + i] = v;
    o1[base4 + i] = v;
  }
}

extern "C" void kernel_launch(void* const* d_in, const int* in_sizes, int n_in,
                              void* d_out, int out_size, void* d_ws,
                              size_t ws_size, hipStream_t stream) {
  const float* z_e = (const float*)d_in[0];  // [N, D] fp32
  const float* emb = (const float*)d_in[1];  // [K, D] fp32
  float* nrm = (float*)d_ws;                 // [K] fp32 scratch

  float* out_st = (float*)d_out;                 // [N, D]
  float* out_q = out_st + (size_t)VQ_N * VQ_D;   // [N, D]
  float* out_idx = out_q + (size_t)VQ_N * VQ_D;  // [N] as float

  vq_norms_kernel<<<(VQ_K + 255) / 256, 256, 0, stream>>>(emb, nrm);
  vq_main_kernel<<<VQ_N / 64, 256, 0, stream>>>(z_e, emb, nrm, out_st, out_q,
                                                out_idx);
}